// Round 1
// 1076.841 us; speedup vs baseline: 1.2377x; 1.2377x over previous
//
#include <hip/hip_runtime.h>

// ---------------------------------------------------------------------------
// MetNet-3 BlockAttention, fused per-window MFMA kernel for gfx950.
// R4: LATENCY ATTACK.
//  - LDS 61440 -> 53344 B  => 3 workgroups/CU (was 2):  q/k zero-pad columns
//    replaced by a shared 16-entry zero block read via pointer-select.
//  - Barriers per block 68 -> 34: removed B->C, C->D, post-stats and
//    pre-epilogue barriers (all wave-internal LDS dependencies).
//  - rel-bias table pre-converted to f32 in prep; per-lane offsets hoisted
//    out of the head loop; bias injected as MFMA accumulator init.
//  - cosine-norm uses rsqrtf; f32 store path uses float4.
//  - XCD-contiguous blockIdx swizzle (2048 = 8*256, bijective) so the four
//    windows sharing each 128B x-line land on the same XCD's L2.
// ---------------------------------------------------------------------------

#define WSZ 8
#define LTOK 64
#define NH 16
#define CCH 256
#define WW2 256
#define HWP 65536          // H*W
#define NWIN 2048          // 2 * 32 * 32 windows

#define TP 258             // sm_t pitch (elements)
#define QP2 18             // sm_q / sm_k pitch (16 data cols, no zero pad)
#define VP2 66             // sm_vt pitch
#define PP2 66             // sm_p pitch
#define OHP 36             // sm_oh pitch

typedef __bf16 bf16x8 __attribute__((ext_vector_type(8)));
typedef float  f32x4  __attribute__((ext_vector_type(4)));
typedef unsigned short u16;
typedef uint4  __attribute__((may_alias)) uint4_a;
typedef float4 __attribute__((may_alias)) float4_a;

__device__ __forceinline__ float b2f(u16 u) {
    return (float)__builtin_bit_cast(__bf16, u);
}
__device__ __forceinline__ u16 f2b(float f) {
    return __builtin_bit_cast(u16, (__bf16)f);
}
__device__ __forceinline__ __bf16 u2b(u16 u) {
    return __builtin_bit_cast(__bf16, u);
}
// dtype-adaptive scalar load of logical element idx
__device__ __forceinline__ float gload(const void* p, int idx, int isf32) {
    return isf32 ? ((const float*)p)[idx] : b2f(((const u16*)p)[idx]);
}

// ---------------------------------------------------------------------------
// Detect: are the float tensors f32 or bf16?  Reads x[0..63] as u16.
// ---------------------------------------------------------------------------
static __global__ void detect_dtype(const u16* __restrict__ xu, int* __restrict__ flag) {
    int lane = threadIdx.x;            // 64 threads
    u16 u = xu[lane];
    int e = (u >> 7) & 0xFF;
    bool plaus = (u == 0) || (e >= 0x6C && e <= 0x86);
    unsigned long long m = __ballot(plaus);
    if (lane == 0) flag[0] = (__popcll(m) >= 56) ? 0 : 1;   // 0 = bf16, 1 = f32
}

// ---------------------------------------------------------------------------
// Prep kernel 1: gwT[col][c] = gamma[c] * qkv_w[c][col]   (768 x 256, bf16)
//                D2[col] = sum_c gamma[c]*W[c][col]        (f32)
//                D3[col] = sum_c beta[c]*W[c][col] + qkv_b (f32)
// ---------------------------------------------------------------------------
static __global__ __launch_bounds__(256) void prep_qkv(
        const void* __restrict__ qkv_w, const void* __restrict__ qkv_b,
        const void* __restrict__ g, const void* __restrict__ be,
        u16* __restrict__ gwT, float* __restrict__ D2, float* __restrict__ D3,
        const int* __restrict__ flagp)
{
    const int isf32 = flagp[0];
    int col = blockIdx.x;          // 0..767
    int c   = threadIdx.x;         // 0..255
    float gv = gload(g, c, isf32), bv = gload(be, c, isf32);
    float wv = gload(qkv_w, c * 768 + col, isf32);
    gwT[col * 256 + c] = f2b(gv * wv);
    float s2 = gv * wv, s3 = bv * wv;
    #pragma unroll
    for (int off = 32; off; off >>= 1) {
        s2 += __shfl_xor(s2, off);
        s3 += __shfl_xor(s3, off);
    }
    __shared__ float p2[4], p3[4];
    int wvid = threadIdx.x >> 6, ln = threadIdx.x & 63;
    if (ln == 0) { p2[wvid] = s2; p3[wvid] = s3; }
    __syncthreads();
    if (threadIdx.x == 0) {
        D2[col] = p2[0] + p2[1] + p2[2] + p2[3];
        D3[col] = p3[0] + p3[1] + p3[2] + p3[3] + gload(qkv_b, col, isf32);
    }
}

// Prep kernel 2: pwT[n][k] = proj_w[k][n]  (256 x 256, bf16)
//                tablef[i] = table[i] as f32 (3600 entries)
static __global__ __launch_bounds__(256) void prep_proj(
        const void* __restrict__ proj_w, u16* __restrict__ pwT,
        const void* __restrict__ table, float* __restrict__ tablef,
        const int* __restrict__ flagp)
{
    const int isf32 = flagp[0];
    int nrow = blockIdx.x, k = threadIdx.x;
    pwT[nrow * 256 + k] = f2b(gload(proj_w, k * 256 + nrow, isf32));
    int gid = blockIdx.x * 256 + threadIdx.x;
    if (gid < (2 * WSZ - 1) * (2 * WSZ - 1) * NH)
        tablef[gid] = gload(table, gid, isf32);
}

// ---------------------------------------------------------------------------
// Main fused kernel: one workgroup (4 waves) per window.  3 WG/CU.
// ---------------------------------------------------------------------------
static __global__ __launch_bounds__(256, 3) void win_attn(
    const void* __restrict__ x, void* __restrict__ out,
    const u16* __restrict__ gwT, const u16* __restrict__ pwT,
    const float* __restrict__ D2, const float* __restrict__ D3,
    const void* __restrict__ proj_b, const void* __restrict__ postg,
    const void* __restrict__ postb, const float* __restrict__ tablef,
    const int* __restrict__ flagp)
{
    __shared__ u16 sm_t[LTOK * TP];      // window tokens t, reused for output
    __shared__ u16 sm_q[LTOK * QP2];     // q-hat  [tok][d] 16 cols
    __shared__ u16 sm_k[LTOK * QP2];     // k-hat  [tok][d]
    __shared__ u16 sm_vt[NH * VP2];      // v^T    [d][tok]
    __shared__ u16 sm_p[LTOK * PP2];     // probs  [tok][key]
    __shared__ u16 sm_oh[LTOK * OHP];    // O head-pair [tok][0..31]
    __shared__ float sm_mean[LTOK], sm_rstd[LTOK];
    __shared__ u16 sm_zero[16];          // K-pad zeros for quad>=2 fragments

    const int isf32 = flagp[0];
    const int tid  = threadIdx.x;
    const int wv   = tid >> 6;
    const int lane = tid & 63;
    const int quad = lane >> 4;
    const int n15  = lane & 15;

    // XCD-contiguous swizzle: 2048 blocks = 8 XCDs x 256-block chunks
    const int b0 = blockIdx.x;
    const int b  = ((b0 & 7) << 8) | (b0 >> 3);
    const int nb = b >> 10, wh = (b >> 5) & 31, wwi = b & 31;
    const int base = nb * (CCH * HWP) + wh * (8 * WW2) + wwi * 8; // + c*HWP + i*WW2 + j

    if (tid < 16) sm_zero[tid] = 0;

    // ---- Phase 0: load window into sm_t ----
    if (isf32) {
        const float* xf = (const float*)x;
        #pragma unroll
        for (int r = 0; r < 8; ++r) {
            int s = tid + r * 256;
            int c = s >> 3, i = s & 7;
            const float* src = xf + base + c * HWP + i * WW2;
            float4 a = *(const float4_a*)(src);
            float4 d = *(const float4_a*)(src + 4);
            u16* dst = &sm_t[(i * 8) * TP + c];
            dst[0 * TP] = f2b(a.x);  dst[1 * TP] = f2b(a.y);
            dst[2 * TP] = f2b(a.z);  dst[3 * TP] = f2b(a.w);
            dst[4 * TP] = f2b(d.x);  dst[5 * TP] = f2b(d.y);
            dst[6 * TP] = f2b(d.z);  dst[7 * TP] = f2b(d.w);
        }
    } else {
        const u16* xu = (const u16*)x;
        #pragma unroll
        for (int r = 0; r < 8; ++r) {
            int s = tid + r * 256;
            int c = s >> 3, i = s & 7;
            const uint4 v = *(const uint4_a*)(xu + base + c * HWP + i * WW2);
            u16* dst = &sm_t[(i * 8) * TP + c];
            dst[0 * TP] = (u16)(v.x & 0xffff);  dst[1 * TP] = (u16)(v.x >> 16);
            dst[2 * TP] = (u16)(v.y & 0xffff);  dst[3 * TP] = (u16)(v.y >> 16);
            dst[4 * TP] = (u16)(v.z & 0xffff);  dst[5 * TP] = (u16)(v.z >> 16);
            dst[6 * TP] = (u16)(v.w & 0xffff);  dst[7 * TP] = (u16)(v.w >> 16);
        }
    }
    __syncthreads();   // sm_t + sm_zero visible to all waves

    // ---- Phase 0b: pre-LN stats (4 threads per token) ----
    // sm_mean/sm_rstd for token l are produced by threads 4l..4l+3, which sit
    // in the same wave that consumes them below -> no barrier needed after.
    {
        int l = tid >> 2, g = tid & 3;
        float s = 0.f, ss = 0.f;
        const u16* row = &sm_t[l * TP + g * 64];
        #pragma unroll
        for (int e = 0; e < 64; ++e) {
            float a = b2f(row[e]);
            s += a; ss += a * a;
        }
        s += __shfl_xor(s, 1); ss += __shfl_xor(ss, 1);
        s += __shfl_xor(s, 2); ss += __shfl_xor(ss, 2);
        if (g == 0) {
            float mean = s * (1.f / 256.f);
            float var  = ss * (1.f / 256.f) - mean * mean;
            sm_mean[l] = mean;
            sm_rstd[l] = rsqrtf(var + 1e-5f);
        }
    }

    // per-lane row constants (C/D rows: tok = wv*16 + quad*4 + r)
    float s4[4], ms4[4];
    #pragma unroll
    for (int r = 0; r < 4; ++r) {
        int tok = wv * 16 + quad * 4 + r;
        float mu = sm_mean[tok], sd = sm_rstd[tok];
        s4[r] = sd; ms4[r] = -mu * sd;
    }

    // hoist QKV A-fragments (row = wv*16 + n15) into registers
    bf16x8 afr[8];
    {
        const u16* arow = &sm_t[(wv * 16 + n15) * TP];
        #pragma unroll
        for (int kb = 0; kb < 8; ++kb) {
            #pragma unroll
            for (int j = 0; j < 8; ++j)
                afr[kb][j] = u2b(arow[kb * 32 + quad * 8 + j]);
        }
    }

    // hoist head-invariant rel-bias table offsets (idx*16; +h per head)
    int toff[4][4];
    #pragma unroll
    for (int ct = 0; ct < 4; ++ct) {
        int key = ct * 16 + n15, im = key >> 3, jm = key & 7;
        #pragma unroll
        for (int r = 0; r < 4; ++r) {
            int tok = wv * 16 + quad * 4 + r;
            int il = tok >> 3, jl = tok & 7;
            toff[ct][r] = ((il - im + 7) * 15 + (jl - jm + 7)) * 16;
        }
    }

    f32x4 accp[16];
    #pragma unroll
    for (int t2 = 0; t2 < 16; ++t2) accp[t2] = f32x4{0.f, 0.f, 0.f, 0.f};
    const f32x4 zero4 = f32x4{0.f, 0.f, 0.f, 0.f};

    // =================== head loop (2 barriers per head) ===================
    for (int h = 0; h < 16; ++h) {
        // --- A: QKV GEMM for this head (wave w: token rows 16w..16w+16) ---
        f32x4 aq = zero4, ak = zero4, av = zero4;
        const u16* gq = &gwT[(h * 16 + n15) * 256 + quad * 8];
        const u16* gk = gq + 256 * 256;
        const u16* gv = gq + 512 * 256;
        #pragma unroll
        for (int kb = 0; kb < 8; ++kb) {
            bf16x8 bq = __builtin_bit_cast(bf16x8, *(const uint4_a*)(gq + kb * 32));
            bf16x8 bk = __builtin_bit_cast(bf16x8, *(const uint4_a*)(gk + kb * 32));
            bf16x8 bv = __builtin_bit_cast(bf16x8, *(const uint4_a*)(gv + kb * 32));
            aq = __builtin_amdgcn_mfma_f32_16x16x32_bf16(afr[kb], bq, aq, 0, 0, 0);
            ak = __builtin_amdgcn_mfma_f32_16x16x32_bf16(afr[kb], bk, ak, 0, 0, 0);
            av = __builtin_amdgcn_mfma_f32_16x16x32_bf16(afr[kb], bv, av, 0, 0, 0);
        }
        // affine LN-fold epilogue: val = rstd*D1 - mu*rstd*D2 + D3
        float d2q = D2[h * 16 + n15],       d3q = D3[h * 16 + n15];
        float d2k = D2[256 + h * 16 + n15], d3k = D3[256 + h * 16 + n15];
        float d2v = D2[512 + h * 16 + n15], d3v = D3[512 + h * 16 + n15];
        float qv[4], kv[4], vv[4];
        #pragma unroll
        for (int r = 0; r < 4; ++r) {
            qv[r] = s4[r] * aq[r] + ms4[r] * d2q + d3q;
            kv[r] = s4[r] * ak[r] + ms4[r] * d2k + d3k;
            vv[r] = s4[r] * av[r] + ms4[r] * d2v + d3v;
        }
        // cosine normalize q,k per token (reduce over d = lane&15 group)
        #pragma unroll
        for (int r = 0; r < 4; ++r) {
            float sq = qv[r] * qv[r], sk = kv[r] * kv[r];
            sq += __shfl_xor(sq, 1); sk += __shfl_xor(sk, 1);
            sq += __shfl_xor(sq, 2); sk += __shfl_xor(sk, 2);
            sq += __shfl_xor(sq, 4); sk += __shfl_xor(sk, 4);
            sq += __shfl_xor(sq, 8); sk += __shfl_xor(sk, 8);
            qv[r] *= rsqrtf(fmaxf(sq, 1e-24f));
            kv[r] *= rsqrtf(fmaxf(sk, 1e-24f));
        }
        #pragma unroll
        for (int r = 0; r < 4; ++r) {
            int tok = wv * 16 + quad * 4 + r;
            sm_q[tok * QP2 + n15] = f2b(qv[r]);
            sm_k[tok * QP2 + n15] = f2b(kv[r]);
            sm_vt[n15 * VP2 + tok] = f2b(vv[r]);   // v^T, scalar write
        }
        __syncthreads();   // k, vt cross-wave visibility (q is wave-private)

        // --- B: scores = q-hat @ k-hat^T (+bias as acc init), softmax ---
        f32x4 sc[4];
        {
            bf16x8 aqf;
            const u16* qrow = (quad < 2) ? &sm_q[(wv * 16 + n15) * QP2 + quad * 8]
                                         : sm_zero;
            #pragma unroll
            for (int j = 0; j < 8; ++j) aqf[j] = u2b(qrow[j]);
            #pragma unroll
            for (int ct = 0; ct < 4; ++ct) {
                bf16x8 bkf;
                const u16* krow = (quad < 2) ? &sm_k[(ct * 16 + n15) * QP2 + quad * 8]
                                             : sm_zero;
                #pragma unroll
                for (int j = 0; j < 8; ++j) bkf[j] = u2b(krow[j]);
                f32x4 bias;
                #pragma unroll
                for (int r = 0; r < 4; ++r) bias[r] = tablef[toff[ct][r] + h];
                sc[ct] = __builtin_amdgcn_mfma_f32_16x16x32_bf16(aqf, bkf, bias, 0, 0, 0);
            }
        }
        #pragma unroll
        for (int r = 0; r < 4; ++r) {
            float mx = fmaxf(fmaxf(sc[0][r], sc[1][r]), fmaxf(sc[2][r], sc[3][r]));
            mx = fmaxf(mx, __shfl_xor(mx, 1));
            mx = fmaxf(mx, __shfl_xor(mx, 2));
            mx = fmaxf(mx, __shfl_xor(mx, 4));
            mx = fmaxf(mx, __shfl_xor(mx, 8));
            float e0 = __expf(sc[0][r] - mx), e1 = __expf(sc[1][r] - mx);
            float e2 = __expf(sc[2][r] - mx), e3 = __expf(sc[3][r] - mx);
            float sm = e0 + e1 + e2 + e3;
            sm += __shfl_xor(sm, 1); sm += __shfl_xor(sm, 2);
            sm += __shfl_xor(sm, 4); sm += __shfl_xor(sm, 8);
            float inv = 1.f / sm;
            int tok = wv * 16 + quad * 4 + r;
            sm_p[tok * PP2 +  0 + n15] = f2b(e0 * inv);
            sm_p[tok * PP2 + 16 + n15] = f2b(e1 * inv);
            sm_p[tok * PP2 + 32 + n15] = f2b(e2 * inv);
            sm_p[tok * PP2 + 48 + n15] = f2b(e3 * inv);
        }
        // NO barrier: sm_p rows read in C are the same wave's rows.

        // --- C: O_h = P @ V ---
        f32x4 ov = zero4;
        #pragma unroll
        for (int ks = 0; ks < 2; ++ks) {
            bf16x8 ap, bvf;
            const u16* prow = &sm_p[(wv * 16 + n15) * PP2 + ks * 32 + quad * 8];
            const u16* vrow = &sm_vt[n15 * VP2 + ks * 32 + quad * 8];
            #pragma unroll
            for (int j = 0; j < 8; ++j) { ap[j] = u2b(prow[j]); bvf[j] = u2b(vrow[j]); }
            ov = __builtin_amdgcn_mfma_f32_16x16x32_bf16(ap, bvf, ov, 0, 0, 0);
        }
        #pragma unroll
        for (int r = 0; r < 4; ++r) {
            int tok = wv * 16 + quad * 4 + r;
            sm_oh[tok * OHP + (h & 1) * 16 + n15] = f2b(ov[r]);
        }
        // NO barrier: sm_oh rows read in D are the same wave's rows.

        // --- D: every odd head, accumulate proj for the head pair (K=32) ---
        if (h & 1) {
            int hp = h >> 1;
            bf16x8 aof;
            const u16* orow = &sm_oh[(wv * 16 + n15) * OHP + quad * 8];
            #pragma unroll
            for (int j = 0; j < 8; ++j) aof[j] = u2b(orow[j]);
            const u16* pwb = &pwT[n15 * 256 + hp * 32 + quad * 8];
            #pragma unroll
            for (int t2 = 0; t2 < 16; ++t2) {
                bf16x8 bpf = __builtin_bit_cast(bf16x8, *(const uint4_a*)(pwb + t2 * 16 * 256));
                accp[t2] = __builtin_amdgcn_mfma_f32_16x16x32_bf16(aof, bpf, accp[t2], 0, 0, 0);
            }
        }
        __syncthreads();   // protect sm_k / sm_vt rewrite next head
    }

    // =================== epilogue ===================
    {
        // out1 = t + o@proj_w + proj_b   (in place in accp)
        #pragma unroll
        for (int t2 = 0; t2 < 16; ++t2) {
            int col = t2 * 16 + n15;
            float pb = gload(proj_b, col, isf32);
            #pragma unroll
            for (int r = 0; r < 4; ++r) {
                int tok = wv * 16 + quad * 4 + r;
                accp[t2][r] += pb + b2f(sm_t[tok * TP + col]);
            }
        }
        // post-LN row stats over 256 channels
        float sr[4] = {0, 0, 0, 0}, ssr[4] = {0, 0, 0, 0};
        #pragma unroll
        for (int t2 = 0; t2 < 16; ++t2) {
            #pragma unroll
            for (int r = 0; r < 4; ++r) { float v = accp[t2][r]; sr[r] += v; ssr[r] += v * v; }
        }
        #pragma unroll
        for (int r = 0; r < 4; ++r) {
            sr[r] += __shfl_xor(sr[r], 1); ssr[r] += __shfl_xor(ssr[r], 1);
            sr[r] += __shfl_xor(sr[r], 2); ssr[r] += __shfl_xor(ssr[r], 2);
            sr[r] += __shfl_xor(sr[r], 4); ssr[r] += __shfl_xor(ssr[r], 4);
            sr[r] += __shfl_xor(sr[r], 8); ssr[r] += __shfl_xor(ssr[r], 8);
        }
        float mean2[4], rs2[4];
        #pragma unroll
        for (int r = 0; r < 4; ++r) {
            float m = sr[r] * (1.f / 256.f);
            float v = ssr[r] * (1.f / 256.f) - m * m;
            mean2[r] = m; rs2[r] = rsqrtf(v + 1e-5f);
        }
        // NO barrier: each wave reads and rewrites only its own sm_t rows.
        #pragma unroll
        for (int t2 = 0; t2 < 16; ++t2) {
            int col = t2 * 16 + n15;
            float pg = gload(postg, col, isf32), pb2 = gload(postb, col, isf32);
            #pragma unroll
            for (int r = 0; r < 4; ++r) {
                int tok = wv * 16 + quad * 4 + r;
                float o1 = accp[t2][r];
                float fin = o1 + (o1 - mean2[r]) * rs2[r] * pg + pb2;
                sm_t[tok * TP + col] = f2b(fin);
            }
        }
    }
    __syncthreads();   // store phase reads sm_t transposed (cross-wave)

    // ---- store (mirror of load) ----
    if (isf32) {
        float* outf = (float*)out;
        #pragma unroll
        for (int r = 0; r < 8; ++r) {
            int s = tid + r * 256;
            int c = s >> 3, i = s & 7;
            const u16* src = &sm_t[(i * 8) * TP + c];
            float* dst = outf + base + c * HWP + i * WW2;
            float4 a, d;
            a.x = b2f(src[0 * TP]); a.y = b2f(src[1 * TP]);
            a.z = b2f(src[2 * TP]); a.w = b2f(src[3 * TP]);
            d.x = b2f(src[4 * TP]); d.y = b2f(src[5 * TP]);
            d.z = b2f(src[6 * TP]); d.w = b2f(src[7 * TP]);
            *(float4_a*)dst = a;
            *(float4_a*)(dst + 4) = d;
        }
    } else {
        u16* outu = (u16*)out;
        #pragma unroll
        for (int r = 0; r < 8; ++r) {
            int s = tid + r * 256;
            int c = s >> 3, i = s & 7;
            const u16* src = &sm_t[(i * 8) * TP + c];
            uint4 v;
            v.x = (unsigned)src[0 * TP] | ((unsigned)src[1 * TP] << 16);
            v.y = (unsigned)src[2 * TP] | ((unsigned)src[3 * TP] << 16);
            v.z = (unsigned)src[4 * TP] | ((unsigned)src[5 * TP] << 16);
            v.w = (unsigned)src[6 * TP] | ((unsigned)src[7 * TP] << 16);
            *(uint4_a*)(outu + base + c * HWP + i * WW2) = v;
        }
    }
}

// ---------------------------------------------------------------------------
extern "C" void kernel_launch(void* const* d_in, const int* in_sizes, int n_in,
                              void* d_out, int out_size, void* d_ws, size_t ws_size,
                              hipStream_t stream) {
    const void* x     = d_in[0];
    const void* preg  = d_in[1];
    const void* preb  = d_in[2];
    const void* postg = d_in[3];
    const void* postb = d_in[4];
    const void* qkvw  = d_in[5];
    const void* qkvb  = d_in[6];
    const void* projw = d_in[7];
    const void* projb = d_in[8];
    const void* table = d_in[9];

    char* ws = (char*)d_ws;
    u16*   gwT = (u16*)(ws);                  // 768*256*2 = 393216
    u16*   pwT = (u16*)(ws + 393216);         // 256*256*2 = 131072  -> 524288
    float* D2  = (float*)(ws + 524288);       // 768*4 -> 527360
    float* D3  = (float*)(ws + 527360);       // 768*4 -> 530432
    float* tbf = (float*)(ws + 530432);       // 3600*4 = 14400 -> 544832
    int*   flg = (int*)(ws + 544832);         // 4 B

    detect_dtype<<<1, 64, 0, stream>>>((const u16*)x, flg);
    prep_qkv<<<768, 256, 0, stream>>>(qkvw, qkvb, preg, preb, gwT, D2, D3, flg);
    prep_proj<<<256, 256, 0, stream>>>(projw, pwT, table, tbf, flg);
    win_attn<<<NWIN, 256, 0, stream>>>(x, d_out, gwT, pwT, D2, D3,
                                       projb, postg, postb, tbf, flg);
}